// Round 1
// baseline (538.310 us; speedup 1.0000x reference)
//
#include <hip/hip_runtime.h>
#include <hip/hip_bf16.h>
#include <math.h>

// ---------------------------------------------------------------------------
// LayerNorm: one block per row (256 elems), block=256
// ---------------------------------------------------------------------------
__global__ __launch_bounds__(256) void ln_kernel(const float* __restrict__ x,
                                                 const float* __restrict__ g,
                                                 const float* __restrict__ bv,
                                                 float* __restrict__ h) {
  int row = blockIdx.x, t = threadIdx.x;
  float v = x[(size_t)row * 256 + t];
  float s = v, q = v * v;
#pragma unroll
  for (int o = 32; o > 0; o >>= 1) {
    s += __shfl_xor(s, o);
    q += __shfl_xor(q, o);
  }
  __shared__ float ss[4], qq[4];
  int w = t >> 6, l = t & 63;
  if (l == 0) { ss[w] = s; qq[w] = q; }
  __syncthreads();
  s = ss[0] + ss[1] + ss[2] + ss[3];
  q = qq[0] + qq[1] + qq[2] + qq[3];
  float mu = s * (1.f / 256.f);
  float var = q * (1.f / 256.f) - mu * mu;
  float inv = rsqrtf(var + 1e-5f);
  h[(size_t)row * 256 + t] = (v - mu) * inv * g[t] + bv[t];
}

// ---------------------------------------------------------------------------
// Tiled fp32 GEMM: C[M,N] = A[M,K] @ B[K,N] (+ bias[n]); BM=BN=64, BK=16
// ---------------------------------------------------------------------------
__global__ __launch_bounds__(256) void gemm_kernel(const float* __restrict__ A,
                                                   const float* __restrict__ Bm,
                                                   const float* __restrict__ bias,
                                                   float* __restrict__ C,
                                                   int M, int N, int K) {
  const int BK = 16;
  __shared__ float As[BK][64];
  __shared__ float Bs[BK][64];
  int tx = threadIdx.x & 15, ty = threadIdx.x >> 4;
  int m0 = blockIdx.y * 64, n0 = blockIdx.x * 64;
  float acc[4][4] = {};
  for (int k0 = 0; k0 < K; k0 += BK) {
    {
      int r = threadIdx.x >> 2;
      int c4 = (threadIdx.x & 3) * 4;
      float4 a = *(const float4*)&A[(size_t)(m0 + r) * K + k0 + c4];
      As[c4 + 0][r] = a.x; As[c4 + 1][r] = a.y;
      As[c4 + 2][r] = a.z; As[c4 + 3][r] = a.w;
    }
    {
      int kk = threadIdx.x >> 4;
      int c4 = (threadIdx.x & 15) * 4;
      *(float4*)&Bs[kk][c4] = *(const float4*)&Bm[(size_t)(k0 + kk) * N + n0 + c4];
    }
    __syncthreads();
#pragma unroll
    for (int kk = 0; kk < BK; kk++) {
      float a[4], bb[4];
#pragma unroll
      for (int r = 0; r < 4; r++) a[r] = As[kk][ty * 4 + r];
#pragma unroll
      for (int c = 0; c < 4; c++) bb[c] = Bs[kk][tx * 4 + c];
#pragma unroll
      for (int r = 0; r < 4; r++)
#pragma unroll
        for (int c = 0; c < 4; c++) acc[r][c] = fmaf(a[r], bb[c], acc[r][c]);
    }
    __syncthreads();
  }
#pragma unroll
  for (int r = 0; r < 4; r++) {
    int row = m0 + ty * 4 + r;
#pragma unroll
    for (int c = 0; c < 4; c++) {
      int col = n0 + tx * 4 + c;
      float val = acc[r][c] + (bias ? bias[col] : 0.f);
      C[(size_t)row * N + col] = val;
    }
  }
}

// ---------------------------------------------------------------------------
// RoPE + split qkv (2048 x 768) -> q,k,v in (B,H,N,D) layout
// ---------------------------------------------------------------------------
__global__ __launch_bounds__(256) void rope_split(const float* __restrict__ qkv,
                                                  float* __restrict__ qo,
                                                  float* __restrict__ ko,
                                                  float* __restrict__ vo) {
  int row = blockIdx.x;           // b*1024 + n
  int b = row >> 10, n = row & 1023;
  int t = threadIdx.x;            // h*32 + d
  int hh = t >> 5, d = t & 31;
  const float* base = qkv + (size_t)row * 768;
  float vv = base[512 + t];
  int f = d & 15;
  float inv_freq = powf(10000.0f, -(float)f / 16.0f);
  float ang = (float)n * inv_freq;
  float sn, cs;
  sincosf(ang, &sn, &cs);
  float q1 = base[hh * 32 + f], q2 = base[hh * 32 + f + 16];
  float k1 = base[256 + hh * 32 + f], k2 = base[256 + hh * 32 + f + 16];
  float qr = (d < 16) ? (q1 * cs - q2 * sn) : (q2 * cs + q1 * sn);
  float kr = (d < 16) ? (k1 * cs - k2 * sn) : (k2 * cs + k1 * sn);
  size_t oidx = ((size_t)(b * 8 + hh) * 1024 + n) * 32 + d;
  qo[oidx] = qr;
  ko[oidx] = kr;
  vo[oidx] = vv;
}

// ---------------------------------------------------------------------------
// Fused attention + relational bias + online softmax + PV
// grid = B * (N/8) = 256 blocks, 256 threads.
// Per j-tile (32): phase A bias MLP (thread=(i,j) pair), phase B scores+softmax
// (thread=(h,j)), phase C PV (thread=(h,d)).
// ---------------------------------------------------------------------------
__global__ __launch_bounds__(256) void attn_kernel(
    const float* __restrict__ q, const float* __restrict__ k,
    const float* __restrict__ v, const float* __restrict__ coords,
    const float* __restrict__ vels, const float* __restrict__ w1,
    const float* __restrict__ b1, const float* __restrict__ w2,
    const float* __restrict__ b2, float* __restrict__ attn_out) {
  const int b = blockIdx.x >> 7;
  const int i0 = (blockIdx.x & 127) * 8;
  const int t = threadIdx.x;
  const int th = t >> 5;  // i (phase A) / h (phase B,C)
  const int tl = t & 31;  // j (phase A,B) / d (phase C)

  __shared__ float Qs[8][256];       // [i][h*32+d]
  __shared__ float relS[8][8][32];   // [h][i][j]
  __shared__ float pS[8][8][32];     // [h][i][j]
  __shared__ float mS[8][8], lS[8][8], fS[8][8];  // [i][h]
  __shared__ float pack[64][16];     // per-k: w1[0..4][k], b1[k], w2[k][0..7], pad
  __shared__ float civ[8][4];        // ci.x ci.y vi.x vi.y
  __shared__ float b2s[8];

  {
    int kk = t & 63, f = t >> 6;
    float4 val;
    if (f == 0)
      val = make_float4(w1[kk], w1[64 + kk], w1[128 + kk], w1[192 + kk]);
    else if (f == 1)
      val = make_float4(w1[256 + kk], b1[kk], w2[kk * 8], w2[kk * 8 + 1]);
    else if (f == 2)
      val = make_float4(w2[kk * 8 + 2], w2[kk * 8 + 3], w2[kk * 8 + 4], w2[kk * 8 + 5]);
    else
      val = make_float4(w2[kk * 8 + 6], w2[kk * 8 + 7], 0.f, 0.f);
    *(float4*)&pack[kk][f * 4] = val;
  }
  for (int e = t; e < 2048; e += 256) {
    int i = e >> 8, c = e & 255;
    Qs[i][c] = q[((size_t)(b * 8 + (c >> 5)) * 1024 + i0 + i) * 32 + (c & 31)];
  }
  if (t < 32) {
    int i = t >> 2, c = t & 3;
    civ[i][c] = (c < 2) ? coords[(size_t)(b * 1024 + i0 + i) * 2 + c]
                        : vels[(size_t)(b * 1024 + i0 + i) * 2 + (c - 2)];
  }
  if (t < 64) { mS[t >> 3][t & 7] = -1e30f; lS[t >> 3][t & 7] = 0.f; }
  if (t < 8) b2s[t] = b2[t];
  float O[8] = {0.f, 0.f, 0.f, 0.f, 0.f, 0.f, 0.f, 0.f};
  __syncthreads();

  const float scale = 0.17677669529663687f;  // 1/sqrt(32)

  for (int jt = 0; jt < 1024; jt += 32) {
    // ---- phase A: relational bias MLP for pair (i0+th, jt+tl) ----
    {
      float2 cj = *(const float2*)&coords[(size_t)(b * 1024 + jt + tl) * 2];
      float2 vj = *(const float2*)&vels[(size_t)(b * 1024 + jt + tl) * 2];
      float dx0 = civ[th][0] - cj.x, dx1 = civ[th][1] - cj.y;
      float dv0 = civ[th][2] - vj.x, dv1 = civ[th][3] - vj.y;
      float dist = sqrtf(dx0 * dx0 + dx1 * dx1);
      float rel[8];
#pragma unroll
      for (int hh = 0; hh < 8; hh++) rel[hh] = b2s[hh];
#pragma unroll 4
      for (int kk = 0; kk < 64; kk++) {
        float4 p0 = *(float4*)&pack[kk][0];
        float4 p1 = *(float4*)&pack[kk][4];
        float4 p2 = *(float4*)&pack[kk][8];
        float4 p3 = *(float4*)&pack[kk][12];
        float z = fmaf(dx0, p0.x,
                  fmaf(dx1, p0.y,
                  fmaf(dist, p0.z,
                  fmaf(dv0, p0.w, fmaf(dv1, p1.x, p1.y)))));
        float gg = 0.5f * z * (1.0f + erff(z * 0.70710678118654752f));
        rel[0] = fmaf(gg, p1.z, rel[0]);
        rel[1] = fmaf(gg, p1.w, rel[1]);
        rel[2] = fmaf(gg, p2.x, rel[2]);
        rel[3] = fmaf(gg, p2.y, rel[3]);
        rel[4] = fmaf(gg, p2.z, rel[4]);
        rel[5] = fmaf(gg, p2.w, rel[5]);
        rel[6] = fmaf(gg, p3.x, rel[6]);
        rel[7] = fmaf(gg, p3.y, rel[7]);
      }
#pragma unroll
      for (int hh = 0; hh < 8; hh++) relS[hh][th][tl] = rel[hh];
    }
    __syncthreads();
    // ---- phase B: scores + online softmax, thread (h=th, j=tl) ----
    {
      const float* krow = k + ((size_t)(b * 8 + th) * 1024 + jt + tl) * 32;
      float4 kr[8];
#pragma unroll
      for (int e = 0; e < 8; e++) kr[e] = *(const float4*)(krow + e * 4);
      float s[8];
#pragma unroll
      for (int i = 0; i < 8; i++) {
        float acc = 0.f;
#pragma unroll
        for (int e = 0; e < 8; e++) {
          float4 qv = *(const float4*)&Qs[i][th * 32 + e * 4];
          acc = fmaf(qv.x, kr[e].x,
                fmaf(qv.y, kr[e].y,
                fmaf(qv.z, kr[e].z, fmaf(qv.w, kr[e].w, acc))));
        }
        s[i] = fmaf(acc, scale, relS[th][i][tl]);
      }
#pragma unroll
      for (int i = 0; i < 8; i++) {
        float tm = s[i];
#pragma unroll
        for (int o = 16; o > 0; o >>= 1) tm = fmaxf(tm, __shfl_xor(tm, o));
        float mo = mS[i][th];
        float nm = fmaxf(mo, tm);
        float fac = __expf(mo - nm);
        float p = __expf(s[i] - nm);
        float ts = p;
#pragma unroll
        for (int o = 16; o > 0; o >>= 1) ts += __shfl_xor(ts, o);
        pS[th][i][tl] = p;
        if (tl == 0) {
          mS[i][th] = nm;
          fS[i][th] = fac;
          lS[i][th] = lS[i][th] * fac + ts;
        }
      }
    }
    __syncthreads();
    // ---- phase C: PV accumulate, thread (h=th, d=tl) ----
    {
      const float* vcol = v + ((size_t)(b * 8 + th) * 1024 + jt) * 32 + tl;
      float acc[8] = {0.f, 0.f, 0.f, 0.f, 0.f, 0.f, 0.f, 0.f};
#pragma unroll
      for (int j = 0; j < 32; j++) {
        float vv = vcol[(size_t)j * 32];
#pragma unroll
        for (int i = 0; i < 8; i++) acc[i] = fmaf(pS[th][i][j], vv, acc[i]);
      }
#pragma unroll
      for (int i = 0; i < 8; i++) O[i] = O[i] * fS[i][th] + acc[i];
    }
    __syncthreads();
  }
#pragma unroll
  for (int i = 0; i < 8; i++) {
    attn_out[((size_t)b * 1024 + i0 + i) * 256 + t] = O[i] / lS[i][th];
  }
}

// ---------------------------------------------------------------------------
extern "C" void kernel_launch(void* const* d_in, const int* in_sizes, int n_in,
                              void* d_out, int out_size, void* d_ws, size_t ws_size,
                              hipStream_t stream) {
  const float* x      = (const float*)d_in[0];
  const float* coords = (const float*)d_in[1];
  const float* vels   = (const float*)d_in[2];
  const float* ln_g   = (const float*)d_in[3];
  const float* ln_b   = (const float*)d_in[4];
  const float* w_qkv  = (const float*)d_in[5];
  const float* w_o    = (const float*)d_in[6];
  const float* b_o    = (const float*)d_in[7];
  const float* w1     = (const float*)d_in[8];
  const float* b1     = (const float*)d_in[9];
  const float* w2     = (const float*)d_in[10];
  const float* b2     = (const float*)d_in[11];
  float* out = (float*)d_out;

  float* ws   = (float*)d_ws;
  float* h_ln = ws;                  // 2048*256   = 524288
  float* qkv  = h_ln + 524288;       // 2048*768   = 1572864
  float* qb   = qkv + 1572864;       // 2*8*1024*32 = 524288
  float* kb   = qb + 524288;
  float* vb   = kb + 524288;
  float* attn = vb + 524288;         // 2048*256

  ln_kernel<<<2048, 256, 0, stream>>>(x, ln_g, ln_b, h_ln);
  gemm_kernel<<<dim3(12, 32), 256, 0, stream>>>(h_ln, w_qkv, nullptr, qkv, 2048, 768, 256);
  rope_split<<<2048, 256, 0, stream>>>(qkv, qb, kb, vb);
  attn_kernel<<<256, 256, 0, stream>>>(qb, kb, vb, coords, vels, w1, b1, w2, b2, attn);
  gemm_kernel<<<dim3(4, 32), 256, 0, stream>>>(attn, w_o, b_o, out, 2048, 256, 256);
}

// Round 2
// 517.987 us; speedup vs baseline: 1.0392x; 1.0392x over previous
//
#include <hip/hip_runtime.h>
#include <hip/hip_bf16.h>
#include <math.h>

// ---------------------------------------------------------------------------
// LayerNorm: one block per row (256 elems), block=256
// ---------------------------------------------------------------------------
__global__ __launch_bounds__(256) void ln_kernel(const float* __restrict__ x,
                                                 const float* __restrict__ g,
                                                 const float* __restrict__ bv,
                                                 float* __restrict__ h) {
  int row = blockIdx.x, t = threadIdx.x;
  float v = x[(size_t)row * 256 + t];
  float s = v, q = v * v;
#pragma unroll
  for (int o = 32; o > 0; o >>= 1) {
    s += __shfl_xor(s, o);
    q += __shfl_xor(q, o);
  }
  __shared__ float ss[4], qq[4];
  int w = t >> 6, l = t & 63;
  if (l == 0) { ss[w] = s; qq[w] = q; }
  __syncthreads();
  s = ss[0] + ss[1] + ss[2] + ss[3];
  q = qq[0] + qq[1] + qq[2] + qq[3];
  float mu = s * (1.f / 256.f);
  float var = q * (1.f / 256.f) - mu * mu;
  float inv = rsqrtf(var + 1e-5f);
  h[(size_t)row * 256 + t] = (v - mu) * inv * g[t] + bv[t];
}

// ---------------------------------------------------------------------------
// Tiled fp32 GEMM: C[M,N] = A[M,K] @ B[K,N] (+ bias[n]); BM=BN=64, BK=16
// ---------------------------------------------------------------------------
__global__ __launch_bounds__(256) void gemm_kernel(const float* __restrict__ A,
                                                   const float* __restrict__ Bm,
                                                   const float* __restrict__ bias,
                                                   float* __restrict__ C,
                                                   int M, int N, int K) {
  const int BK = 16;
  __shared__ float As[BK][64];
  __shared__ float Bs[BK][64];
  int tx = threadIdx.x & 15, ty = threadIdx.x >> 4;
  int m0 = blockIdx.y * 64, n0 = blockIdx.x * 64;
  float acc[4][4] = {};
  for (int k0 = 0; k0 < K; k0 += BK) {
    {
      int r = threadIdx.x >> 2;
      int c4 = (threadIdx.x & 3) * 4;
      float4 a = *(const float4*)&A[(size_t)(m0 + r) * K + k0 + c4];
      As[c4 + 0][r] = a.x; As[c4 + 1][r] = a.y;
      As[c4 + 2][r] = a.z; As[c4 + 3][r] = a.w;
    }
    {
      int kk = threadIdx.x >> 4;
      int c4 = (threadIdx.x & 15) * 4;
      *(float4*)&Bs[kk][c4] = *(const float4*)&Bm[(size_t)(k0 + kk) * N + n0 + c4];
    }
    __syncthreads();
#pragma unroll
    for (int kk = 0; kk < BK; kk++) {
      float a[4], bb[4];
#pragma unroll
      for (int r = 0; r < 4; r++) a[r] = As[kk][ty * 4 + r];
#pragma unroll
      for (int c = 0; c < 4; c++) bb[c] = Bs[kk][tx * 4 + c];
#pragma unroll
      for (int r = 0; r < 4; r++)
#pragma unroll
        for (int c = 0; c < 4; c++) acc[r][c] = fmaf(a[r], bb[c], acc[r][c]);
    }
    __syncthreads();
  }
#pragma unroll
  for (int r = 0; r < 4; r++) {
    int row = m0 + ty * 4 + r;
#pragma unroll
    for (int c = 0; c < 4; c++) {
      int col = n0 + tx * 4 + c;
      float val = acc[r][c] + (bias ? bias[col] : 0.f);
      C[(size_t)row * N + col] = val;
    }
  }
}

// ---------------------------------------------------------------------------
// RoPE + split qkv (2048 x 768) -> q,k,v in (B,H,N,D) layout
// ---------------------------------------------------------------------------
__global__ __launch_bounds__(256) void rope_split(const float* __restrict__ qkv,
                                                  float* __restrict__ qo,
                                                  float* __restrict__ ko,
                                                  float* __restrict__ vo) {
  int row = blockIdx.x;           // b*1024 + n
  int b = row >> 10, n = row & 1023;
  int t = threadIdx.x;            // h*32 + d
  int hh = t >> 5, d = t & 31;
  const float* base = qkv + (size_t)row * 768;
  float vv = base[512 + t];
  int f = d & 15;
  float inv_freq = powf(10000.0f, -(float)f / 16.0f);
  float ang = (float)n * inv_freq;
  float sn, cs;
  sincosf(ang, &sn, &cs);
  float q1 = base[hh * 32 + f], q2 = base[hh * 32 + f + 16];
  float k1 = base[256 + hh * 32 + f], k2 = base[256 + hh * 32 + f + 16];
  float qr = (d < 16) ? (q1 * cs - q2 * sn) : (q2 * cs + q1 * sn);
  float kr = (d < 16) ? (k1 * cs - k2 * sn) : (k2 * cs + k1 * sn);
  size_t oidx = ((size_t)(b * 8 + hh) * 1024 + n) * 32 + d;
  qo[oidx] = qr;
  ko[oidx] = kr;
  vo[oidx] = vv;
}

// ---------------------------------------------------------------------------
// Fast exact GELU via Abramowitz-Stegun 7.1.26 erf (max err 1.5e-7)
// ---------------------------------------------------------------------------
__device__ __forceinline__ float gelu_fast(float z) {
  float s = z * 0.70710678118654752f;
  float a = fabsf(s);
  float t = __builtin_amdgcn_rcpf(fmaf(0.3275911f, a, 1.0f));
  float poly = t * fmaf(t, fmaf(t, fmaf(t, fmaf(t, 1.061405429f, -1.453152027f),
                                        1.421413741f),
                                -0.284496736f),
                        0.254829592f);
  float e = __expf(-a * a);
  float erf_a = fmaf(-poly, e, 1.0f);
  float erf_s = copysignf(erf_a, s);
  return 0.5f * z * (1.0f + erf_s);
}

// ---------------------------------------------------------------------------
// Fused attention + relational bias + online softmax + PV, j-split by 4.
// grid = B * (N/8) * 4 = 1024 blocks, 256 threads, 4 blocks/CU target.
// Each block does j in [js*256, js*256+256), writes partial O (unnormalized)
// and per-(i,h) (m, l) for the combine kernel.
// ---------------------------------------------------------------------------
__global__ __launch_bounds__(256, 4) void attn_kernel(
    const float* __restrict__ q, const float* __restrict__ k,
    const float* __restrict__ v, const float* __restrict__ coords,
    const float* __restrict__ vels, const float* __restrict__ w1,
    const float* __restrict__ b1, const float* __restrict__ w2,
    const float* __restrict__ b2, float* __restrict__ Opart,
    float* __restrict__ ml) {
  const int ig = blockIdx.x & 127;        // i-group
  const int js = (blockIdx.x >> 7) & 3;   // j-split index
  const int b = blockIdx.x >> 9;
  const int i0 = ig * 8;
  const int j0 = js * 256;
  const int t = threadIdx.x;
  const int th = t >> 5;  // i (phase A) / h (phase B,C)
  const int tl = t & 31;  // j (phase A,B) / d (phase C)

  __shared__ float Qs[8][256];       // [i][h*32+d]
  __shared__ float relS[8][8][32];   // [h][i][j]
  __shared__ float pS[8][8][32];     // [h][i][j]
  __shared__ float mS[8][8], lS[8][8], fS[8][8];  // [i][h]
  __shared__ float pack[64][16];     // per-k: w1[0..4][k], b1[k], w2[k][0..7], pad
  __shared__ float civ[8][4];        // ci.x ci.y vi.x vi.y
  __shared__ float b2s[8];

  {
    int kk = t & 63, f = t >> 6;
    float4 val;
    if (f == 0)
      val = make_float4(w1[kk], w1[64 + kk], w1[128 + kk], w1[192 + kk]);
    else if (f == 1)
      val = make_float4(w1[256 + kk], b1[kk], w2[kk * 8], w2[kk * 8 + 1]);
    else if (f == 2)
      val = make_float4(w2[kk * 8 + 2], w2[kk * 8 + 3], w2[kk * 8 + 4], w2[kk * 8 + 5]);
    else
      val = make_float4(w2[kk * 8 + 6], w2[kk * 8 + 7], 0.f, 0.f);
    *(float4*)&pack[kk][f * 4] = val;
  }
  for (int e = t; e < 2048; e += 256) {
    int i = e >> 8, c = e & 255;
    Qs[i][c] = q[((size_t)(b * 8 + (c >> 5)) * 1024 + i0 + i) * 32 + (c & 31)];
  }
  if (t < 32) {
    int i = t >> 2, c = t & 3;
    civ[i][c] = (c < 2) ? coords[(size_t)(b * 1024 + i0 + i) * 2 + c]
                        : vels[(size_t)(b * 1024 + i0 + i) * 2 + (c - 2)];
  }
  if (t < 64) { mS[t >> 3][t & 7] = -1e30f; lS[t >> 3][t & 7] = 0.f; }
  if (t < 8) b2s[t] = b2[t];
  float O[8] = {0.f, 0.f, 0.f, 0.f, 0.f, 0.f, 0.f, 0.f};
  __syncthreads();

  const float scale = 0.17677669529663687f;  // 1/sqrt(32)

  for (int jt = j0; jt < j0 + 256; jt += 32) {
    // ---- phase A: relational bias MLP for pair (i0+th, jt+tl) ----
    {
      float2 cj = *(const float2*)&coords[(size_t)(b * 1024 + jt + tl) * 2];
      float2 vj = *(const float2*)&vels[(size_t)(b * 1024 + jt + tl) * 2];
      float dx0 = civ[th][0] - cj.x, dx1 = civ[th][1] - cj.y;
      float dv0 = civ[th][2] - vj.x, dv1 = civ[th][3] - vj.y;
      float dist = sqrtf(dx0 * dx0 + dx1 * dx1);
      float rel[8];
#pragma unroll
      for (int hh = 0; hh < 8; hh++) rel[hh] = b2s[hh];
#pragma unroll 4
      for (int kk = 0; kk < 64; kk++) {
        float4 p0 = *(float4*)&pack[kk][0];
        float4 p1 = *(float4*)&pack[kk][4];
        float4 p2 = *(float4*)&pack[kk][8];
        float4 p3 = *(float4*)&pack[kk][12];
        float z = fmaf(dx0, p0.x,
                  fmaf(dx1, p0.y,
                  fmaf(dist, p0.z,
                  fmaf(dv0, p0.w, fmaf(dv1, p1.x, p1.y)))));
        float gg = gelu_fast(z);
        rel[0] = fmaf(gg, p1.z, rel[0]);
        rel[1] = fmaf(gg, p1.w, rel[1]);
        rel[2] = fmaf(gg, p2.x, rel[2]);
        rel[3] = fmaf(gg, p2.y, rel[3]);
        rel[4] = fmaf(gg, p2.z, rel[4]);
        rel[5] = fmaf(gg, p2.w, rel[5]);
        rel[6] = fmaf(gg, p3.x, rel[6]);
        rel[7] = fmaf(gg, p3.y, rel[7]);
      }
#pragma unroll
      for (int hh = 0; hh < 8; hh++) relS[hh][th][tl] = rel[hh];
    }
    __syncthreads();
    // ---- phase B: scores + online softmax, thread (h=th, j=tl) ----
    {
      const float* krow = k + ((size_t)(b * 8 + th) * 1024 + jt + tl) * 32;
      float acc[8] = {0.f, 0.f, 0.f, 0.f, 0.f, 0.f, 0.f, 0.f};
#pragma unroll
      for (int e = 0; e < 8; e++) {
        float4 kr = *(const float4*)(krow + e * 4);
#pragma unroll
        for (int i = 0; i < 8; i++) {
          float4 qv = *(const float4*)&Qs[i][th * 32 + e * 4];
          acc[i] = fmaf(qv.x, kr.x,
                   fmaf(qv.y, kr.y,
                   fmaf(qv.z, kr.z, fmaf(qv.w, kr.w, acc[i]))));
        }
      }
#pragma unroll
      for (int i = 0; i < 8; i++) {
        float s = fmaf(acc[i], scale, relS[th][i][tl]);
        float tm = s;
#pragma unroll
        for (int o = 16; o > 0; o >>= 1) tm = fmaxf(tm, __shfl_xor(tm, o));
        float mo = mS[i][th];
        float nm = fmaxf(mo, tm);
        float fac = __expf(mo - nm);
        float p = __expf(s - nm);
        float ts = p;
#pragma unroll
        for (int o = 16; o > 0; o >>= 1) ts += __shfl_xor(ts, o);
        pS[th][i][tl] = p;
        if (tl == 0) {
          mS[i][th] = nm;
          fS[i][th] = fac;
          lS[i][th] = lS[i][th] * fac + ts;
        }
      }
    }
    __syncthreads();
    // ---- phase C: PV accumulate, thread (h=th, d=tl) ----
    {
      const float* vcol = v + ((size_t)(b * 8 + th) * 1024 + jt) * 32 + tl;
      float acc[8] = {0.f, 0.f, 0.f, 0.f, 0.f, 0.f, 0.f, 0.f};
#pragma unroll
      for (int j = 0; j < 32; j++) {
        float vv = vcol[(size_t)j * 32];
#pragma unroll
        for (int i = 0; i < 8; i++) acc[i] = fmaf(pS[th][i][j], vv, acc[i]);
      }
#pragma unroll
      for (int i = 0; i < 8; i++) O[i] = O[i] * fS[i][th] + acc[i];
    }
    __syncthreads();
  }
  // write partial O (unnormalized) and (m, l)
  size_t obase = ((size_t)((b * 4 + js) * 1024) + i0) * 256;
#pragma unroll
  for (int i = 0; i < 8; i++) Opart[obase + (size_t)i * 256 + t] = O[i];
  if (t < 64) {
    int i = t >> 3, hh = t & 7;
    ((float2*)ml)[(((size_t)(b * 4 + js) * 1024) + i0 + i) * 8 + hh] =
        make_float2(mS[i][hh], lS[i][hh]);
  }
}

// ---------------------------------------------------------------------------
// Combine j-split partials: grid = 256 blocks (b, i-group of 8), 256 threads.
// ---------------------------------------------------------------------------
__global__ __launch_bounds__(256) void combine_kernel(
    const float* __restrict__ Opart, const float* __restrict__ ml,
    float* __restrict__ attn) {
  int b = blockIdx.x >> 7, ig = blockIdx.x & 127;
  int i0 = ig * 8;
  int t = threadIdx.x, hh = t >> 5;
#pragma unroll
  for (int i = 0; i < 8; i++) {
    float2 mls[4];
    float M = -1e30f;
#pragma unroll
    for (int js = 0; js < 4; js++) {
      mls[js] = ((const float2*)ml)[(((size_t)(b * 4 + js) * 1024) + i0 + i) * 8 + hh];
      M = fmaxf(M, mls[js].x);
    }
    float L = 0.f, Ov = 0.f;
#pragma unroll
    for (int js = 0; js < 4; js++) {
      float w = __expf(mls[js].x - M);
      L += mls[js].y * w;
      Ov += Opart[(((size_t)(b * 4 + js) * 1024) + i0 + i) * 256 + t] * w;
    }
    attn[((size_t)b * 1024 + i0 + i) * 256 + t] = Ov / L;
  }
}

// ---------------------------------------------------------------------------
extern "C" void kernel_launch(void* const* d_in, const int* in_sizes, int n_in,
                              void* d_out, int out_size, void* d_ws, size_t ws_size,
                              hipStream_t stream) {
  const float* x      = (const float*)d_in[0];
  const float* coords = (const float*)d_in[1];
  const float* vels   = (const float*)d_in[2];
  const float* ln_g   = (const float*)d_in[3];
  const float* ln_b   = (const float*)d_in[4];
  const float* w_qkv  = (const float*)d_in[5];
  const float* w_o    = (const float*)d_in[6];
  const float* b_o    = (const float*)d_in[7];
  const float* w1     = (const float*)d_in[8];
  const float* b1     = (const float*)d_in[9];
  const float* w2     = (const float*)d_in[10];
  const float* b2     = (const float*)d_in[11];
  float* out = (float*)d_out;

  float* ws    = (float*)d_ws;
  float* h_ln  = ws;                  // 524288 floats (dead after qkv gemm)
  float* qkv   = ws + 524288;         // 1572864 floats (dead after rope)
  float* Opart = ws;                  // 2097152 floats, reuses h_ln+qkv
  float* qb    = ws + 2097152;        // 524288 each
  float* kb    = qb + 524288;
  float* vb    = kb + 524288;
  float* attn  = vb + 524288;
  float* ml    = (float*)d_out;       // 131072 floats scratch; final gemm
                                      // fully rewrites d_out afterwards

  ln_kernel<<<2048, 256, 0, stream>>>(x, ln_g, ln_b, h_ln);
  gemm_kernel<<<dim3(12, 32), 256, 0, stream>>>(h_ln, w_qkv, nullptr, qkv, 2048, 768, 256);
  rope_split<<<2048, 256, 0, stream>>>(qkv, qb, kb, vb);
  attn_kernel<<<1024, 256, 0, stream>>>(qb, kb, vb, coords, vels, w1, b1, w2, b2, Opart, ml);
  combine_kernel<<<256, 256, 0, stream>>>(Opart, ml, attn);
  gemm_kernel<<<dim3(4, 32), 256, 0, stream>>>(attn, w_o, b_o, out, 2048, 256, 256);
}

// Round 3
// 423.934 us; speedup vs baseline: 1.2698x; 1.2219x over previous
//
#include <hip/hip_runtime.h>
#include <hip/hip_bf16.h>
#include <math.h>

// ---------------------------------------------------------------------------
// LayerNorm: one block per row (256 elems), block=256
// ---------------------------------------------------------------------------
__global__ __launch_bounds__(256) void ln_kernel(const float* __restrict__ x,
                                                 const float* __restrict__ g,
                                                 const float* __restrict__ bv,
                                                 float* __restrict__ h) {
  int row = blockIdx.x, t = threadIdx.x;
  float v = x[(size_t)row * 256 + t];
  float s = v, q = v * v;
#pragma unroll
  for (int o = 32; o > 0; o >>= 1) {
    s += __shfl_xor(s, o);
    q += __shfl_xor(q, o);
  }
  __shared__ float ss[4], qq[4];
  int w = t >> 6, l = t & 63;
  if (l == 0) { ss[w] = s; qq[w] = q; }
  __syncthreads();
  s = ss[0] + ss[1] + ss[2] + ss[3];
  q = qq[0] + qq[1] + qq[2] + qq[3];
  float mu = s * (1.f / 256.f);
  float var = q * (1.f / 256.f) - mu * mu;
  float inv = rsqrtf(var + 1e-5f);
  h[(size_t)row * 256 + t] = (v - mu) * inv * g[t] + bv[t];
}

// ---------------------------------------------------------------------------
// Tiled fp32 GEMM: C[M,N] = A[M,K] @ B[K,N] (+ bias[n]); BM=BN=64, BK=16
// ---------------------------------------------------------------------------
__global__ __launch_bounds__(256) void gemm_kernel(const float* __restrict__ A,
                                                   const float* __restrict__ Bm,
                                                   const float* __restrict__ bias,
                                                   float* __restrict__ C,
                                                   int M, int N, int K) {
  const int BK = 16;
  __shared__ float As[BK][64];
  __shared__ float Bs[BK][64];
  int tx = threadIdx.x & 15, ty = threadIdx.x >> 4;
  int m0 = blockIdx.y * 64, n0 = blockIdx.x * 64;
  float acc[4][4] = {};
  for (int k0 = 0; k0 < K; k0 += BK) {
    {
      int r = threadIdx.x >> 2;
      int c4 = (threadIdx.x & 3) * 4;
      float4 a = *(const float4*)&A[(size_t)(m0 + r) * K + k0 + c4];
      As[c4 + 0][r] = a.x; As[c4 + 1][r] = a.y;
      As[c4 + 2][r] = a.z; As[c4 + 3][r] = a.w;
    }
    {
      int kk = threadIdx.x >> 4;
      int c4 = (threadIdx.x & 15) * 4;
      *(float4*)&Bs[kk][c4] = *(const float4*)&Bm[(size_t)(k0 + kk) * N + n0 + c4];
    }
    __syncthreads();
#pragma unroll
    for (int kk = 0; kk < BK; kk++) {
      float a[4], bb[4];
#pragma unroll
      for (int r = 0; r < 4; r++) a[r] = As[kk][ty * 4 + r];
#pragma unroll
      for (int c = 0; c < 4; c++) bb[c] = Bs[kk][tx * 4 + c];
#pragma unroll
      for (int r = 0; r < 4; r++)
#pragma unroll
        for (int c = 0; c < 4; c++) acc[r][c] = fmaf(a[r], bb[c], acc[r][c]);
    }
    __syncthreads();
  }
#pragma unroll
  for (int r = 0; r < 4; r++) {
    int row = m0 + ty * 4 + r;
#pragma unroll
    for (int c = 0; c < 4; c++) {
      int col = n0 + tx * 4 + c;
      float val = acc[r][c] + (bias ? bias[col] : 0.f);
      C[(size_t)row * N + col] = val;
    }
  }
}

// ---------------------------------------------------------------------------
// RoPE + split qkv (2048 x 768) -> q,k,v in (B,H,N,D) layout
// ---------------------------------------------------------------------------
__global__ __launch_bounds__(256) void rope_split(const float* __restrict__ qkv,
                                                  float* __restrict__ qo,
                                                  float* __restrict__ ko,
                                                  float* __restrict__ vo) {
  int row = blockIdx.x;           // b*1024 + n
  int b = row >> 10, n = row & 1023;
  int t = threadIdx.x;            // h*32 + d
  int hh = t >> 5, d = t & 31;
  const float* base = qkv + (size_t)row * 768;
  float vv = base[512 + t];
  int f = d & 15;
  float inv_freq = powf(10000.0f, -(float)f / 16.0f);
  float ang = (float)n * inv_freq;
  float sn, cs;
  sincosf(ang, &sn, &cs);
  float q1 = base[hh * 32 + f], q2 = base[hh * 32 + f + 16];
  float k1 = base[256 + hh * 32 + f], k2 = base[256 + hh * 32 + f + 16];
  float qr = (d < 16) ? (q1 * cs - q2 * sn) : (q2 * cs + q1 * sn);
  float kr = (d < 16) ? (k1 * cs - k2 * sn) : (k2 * cs + k1 * sn);
  size_t oidx = ((size_t)(b * 8 + hh) * 1024 + n) * 32 + d;
  qo[oidx] = qr;
  ko[oidx] = kr;
  vo[oidx] = vv;
}

// ---------------------------------------------------------------------------
// Fast exact GELU via Abramowitz-Stegun 7.1.26 erf (max err 1.5e-7)
// ---------------------------------------------------------------------------
__device__ __forceinline__ float gelu_fast(float z) {
  float s = z * 0.70710678118654752f;
  float a = fabsf(s);
  float t = __builtin_amdgcn_rcpf(fmaf(0.3275911f, a, 1.0f));
  float poly = t * fmaf(t, fmaf(t, fmaf(t, fmaf(t, 1.061405429f, -1.453152027f),
                                        1.421413741f),
                                -0.284496736f),
                        0.254829592f);
  float e = __expf(-a * a);
  float erf_a = fmaf(-poly, e, 1.0f);
  float erf_s = copysignf(erf_a, s);
  return 0.5f * z * (1.0f + erf_s);
}

// ---------------------------------------------------------------------------
// Fused attention + relational bias + online softmax + PV, j-split by 4.
// grid = B * 4 * (N/8) = 1024 blocks, 256 threads. No launch_bounds cap
// (R2 lesson: min-waves=4 forced a 64-VGPR cap -> 1.3 GB scratch spills).
// Per j-tile: [B: scores+softmax] bar [C: PV + A(next): bias MLP] bar.
// ---------------------------------------------------------------------------
__global__ __launch_bounds__(256) void attn_kernel(
    const float* __restrict__ q, const float* __restrict__ k,
    const float* __restrict__ v, const float* __restrict__ coords,
    const float* __restrict__ vels, const float* __restrict__ w1,
    const float* __restrict__ b1, const float* __restrict__ w2,
    const float* __restrict__ b2, float* __restrict__ Opart,
    float* __restrict__ ml) {
  const int ig = blockIdx.x & 127;        // i-group
  const int js = (blockIdx.x >> 7) & 3;   // j-split index
  const int b = blockIdx.x >> 9;
  const int i0 = ig * 8;
  const int j0 = js * 256;
  const int t = threadIdx.x;
  const int th = t >> 5;  // i (phase A) / h (phase B,C)
  const int tl = t & 31;  // j (phase A,B) / d (phase C)

  __shared__ float Qs[8][256];       // [i][h*32+d]
  __shared__ float relS[8][8][32];   // [h][i][j]
  __shared__ float pS[8][8][32];     // [h][i][j]
  __shared__ float mS[8][8], lS[8][8], fS[8][8];  // [i][h]
  __shared__ float pack[64][16];     // per-k: w1[0..4][k], b1[k], w2[k][0..7], pad
  __shared__ float civ[8][4];        // ci.x ci.y vi.x vi.y
  __shared__ float b2s[8];

  {
    int kk = t & 63, f = t >> 6;
    float4 val;
    if (f == 0)
      val = make_float4(w1[kk], w1[64 + kk], w1[128 + kk], w1[192 + kk]);
    else if (f == 1)
      val = make_float4(w1[256 + kk], b1[kk], w2[kk * 8], w2[kk * 8 + 1]);
    else if (f == 2)
      val = make_float4(w2[kk * 8 + 2], w2[kk * 8 + 3], w2[kk * 8 + 4], w2[kk * 8 + 5]);
    else
      val = make_float4(w2[kk * 8 + 6], w2[kk * 8 + 7], 0.f, 0.f);
    *(float4*)&pack[kk][f * 4] = val;
  }
  for (int e = t; e < 2048; e += 256) {
    int i = e >> 8, c = e & 255;
    Qs[i][c] = q[((size_t)(b * 8 + (c >> 5)) * 1024 + i0 + i) * 32 + (c & 31)];
  }
  if (t < 32) {
    int i = t >> 2, c = t & 3;
    civ[i][c] = (c < 2) ? coords[(size_t)(b * 1024 + i0 + i) * 2 + c]
                        : vels[(size_t)(b * 1024 + i0 + i) * 2 + (c - 2)];
  }
  if (t < 64) { mS[t >> 3][t & 7] = -1e30f; lS[t >> 3][t & 7] = 0.f; }
  if (t < 8) b2s[t] = b2[t];
  float O[8] = {0.f, 0.f, 0.f, 0.f, 0.f, 0.f, 0.f, 0.f};
  __syncthreads();

  const float scale = 0.17677669529663687f;  // 1/sqrt(32)

  // ---- phase A for the first j-tile ----
#define PHASE_A(JT)                                                            \
  {                                                                            \
    float2 cj = *(const float2*)&coords[(size_t)(b * 1024 + (JT) + tl) * 2];   \
    float2 vj = *(const float2*)&vels[(size_t)(b * 1024 + (JT) + tl) * 2];     \
    float dx0 = civ[th][0] - cj.x, dx1 = civ[th][1] - cj.y;                    \
    float dv0 = civ[th][2] - vj.x, dv1 = civ[th][3] - vj.y;                    \
    float dist = sqrtf(dx0 * dx0 + dx1 * dx1);                                 \
    float rel[8];                                                              \
    _Pragma("unroll")                                                          \
    for (int hh = 0; hh < 8; hh++) rel[hh] = b2s[hh];                          \
    _Pragma("unroll 2")                                                        \
    for (int kk = 0; kk < 64; kk++) {                                          \
      float4 p0 = *(float4*)&pack[kk][0];                                      \
      float4 p1 = *(float4*)&pack[kk][4];                                      \
      float4 p2 = *(float4*)&pack[kk][8];                                      \
      float4 p3 = *(float4*)&pack[kk][12];                                     \
      float z = fmaf(dx0, p0.x,                                                \
                fmaf(dx1, p0.y,                                                \
                fmaf(dist, p0.z,                                               \
                fmaf(dv0, p0.w, fmaf(dv1, p1.x, p1.y)))));                     \
      float gg = gelu_fast(z);                                                 \
      rel[0] = fmaf(gg, p1.z, rel[0]);                                         \
      rel[1] = fmaf(gg, p1.w, rel[1]);                                         \
      rel[2] = fmaf(gg, p2.x, rel[2]);                                         \
      rel[3] = fmaf(gg, p2.y, rel[3]);                                         \
      rel[4] = fmaf(gg, p2.z, rel[4]);                                         \
      rel[5] = fmaf(gg, p2.w, rel[5]);                                         \
      rel[6] = fmaf(gg, p3.x, rel[6]);                                         \
      rel[7] = fmaf(gg, p3.y, rel[7]);                                         \
    }                                                                          \
    _Pragma("unroll")                                                          \
    for (int hh = 0; hh < 8; hh++) relS[hh][th][tl] = rel[hh];                 \
  }

  PHASE_A(j0)

  for (int jt = j0; jt < j0 + 256; jt += 32) {
    __syncthreads();  // relS(jt) ready
    // ---- phase B: scores + online softmax, thread (h=th, j=tl) ----
    {
      const float* krow = k + ((size_t)(b * 8 + th) * 1024 + jt + tl) * 32;
      float acc[8] = {0.f, 0.f, 0.f, 0.f, 0.f, 0.f, 0.f, 0.f};
#pragma unroll
      for (int e = 0; e < 8; e++) {
        float4 kr = *(const float4*)(krow + e * 4);
#pragma unroll
        for (int i = 0; i < 8; i++) {
          float4 qv = *(const float4*)&Qs[i][th * 32 + e * 4];
          acc[i] = fmaf(qv.x, kr.x,
                   fmaf(qv.y, kr.y,
                   fmaf(qv.z, kr.z, fmaf(qv.w, kr.w, acc[i]))));
        }
      }
#pragma unroll
      for (int i = 0; i < 8; i++) {
        float s = fmaf(acc[i], scale, relS[th][i][tl]);
        float tm = s;
#pragma unroll
        for (int o = 16; o > 0; o >>= 1) tm = fmaxf(tm, __shfl_xor(tm, o));
        float mo = mS[i][th];
        float nm = fmaxf(mo, tm);
        float fac = __expf(mo - nm);
        float p = __expf(s - nm);
        float ts = p;
#pragma unroll
        for (int o = 16; o > 0; o >>= 1) ts += __shfl_xor(ts, o);
        pS[th][i][tl] = p;
        if (tl == 0) {
          mS[i][th] = nm;
          fS[i][th] = fac;
          lS[i][th] = lS[i][th] * fac + ts;
        }
      }
    }
    __syncthreads();  // pS ready; relS free for next tile
    // ---- phase C: PV accumulate, thread (h=th, d=tl) ----
    {
      const float* vcol = v + ((size_t)(b * 8 + th) * 1024 + jt) * 32 + tl;
      float acc[8] = {0.f, 0.f, 0.f, 0.f, 0.f, 0.f, 0.f, 0.f};
#pragma unroll 8
      for (int j = 0; j < 32; j++) {
        float vv = vcol[(size_t)j * 32];
#pragma unroll
        for (int i = 0; i < 8; i++) acc[i] = fmaf(pS[th][i][j], vv, acc[i]);
      }
#pragma unroll
      for (int i = 0; i < 8; i++) O[i] = O[i] * fS[i][th] + acc[i];
    }
    // ---- phase A for next tile (shares barrier region with C) ----
    if (jt + 32 < j0 + 256) PHASE_A(jt + 32)
  }
  // write partial O (unnormalized) and (m, l)
  size_t obase = ((size_t)((b * 4 + js) * 1024) + i0) * 256;
#pragma unroll
  for (int i = 0; i < 8; i++) Opart[obase + (size_t)i * 256 + t] = O[i];
  if (t < 64) {
    int i = t >> 3, hh = t & 7;
    ((float2*)ml)[(((size_t)(b * 4 + js) * 1024) + i0 + i) * 8 + hh] =
        make_float2(mS[i][hh], lS[i][hh]);
  }
#undef PHASE_A
}

// ---------------------------------------------------------------------------
// Combine j-split partials: grid = 256 blocks (b, i-group of 8), 256 threads.
// ---------------------------------------------------------------------------
__global__ __launch_bounds__(256) void combine_kernel(
    const float* __restrict__ Opart, const float* __restrict__ ml,
    float* __restrict__ attn) {
  int b = blockIdx.x >> 7, ig = blockIdx.x & 127;
  int i0 = ig * 8;
  int t = threadIdx.x, hh = t >> 5;
#pragma unroll
  for (int i = 0; i < 8; i++) {
    float2 mls[4];
    float M = -1e30f;
#pragma unroll
    for (int js = 0; js < 4; js++) {
      mls[js] = ((const float2*)ml)[(((size_t)(b * 4 + js) * 1024) + i0 + i) * 8 + hh];
      M = fmaxf(M, mls[js].x);
    }
    float L = 0.f, Ov = 0.f;
#pragma unroll
    for (int js = 0; js < 4; js++) {
      float w = __expf(mls[js].x - M);
      L += mls[js].y * w;
      Ov += Opart[(((size_t)(b * 4 + js) * 1024) + i0 + i) * 256 + t] * w;
    }
    attn[((size_t)b * 1024 + i0 + i) * 256 + t] = Ov / L;
  }
}

// ---------------------------------------------------------------------------
extern "C" void kernel_launch(void* const* d_in, const int* in_sizes, int n_in,
                              void* d_out, int out_size, void* d_ws, size_t ws_size,
                              hipStream_t stream) {
  const float* x      = (const float*)d_in[0];
  const float* coords = (const float*)d_in[1];
  const float* vels   = (const float*)d_in[2];
  const float* ln_g   = (const float*)d_in[3];
  const float* ln_b   = (const float*)d_in[4];
  const float* w_qkv  = (const float*)d_in[5];
  const float* w_o    = (const float*)d_in[6];
  const float* b_o    = (const float*)d_in[7];
  const float* w1     = (const float*)d_in[8];
  const float* b1     = (const float*)d_in[9];
  const float* w2     = (const float*)d_in[10];
  const float* b2     = (const float*)d_in[11];
  float* out = (float*)d_out;

  float* ws    = (float*)d_ws;
  float* h_ln  = ws;                  // 524288 floats (dead after qkv gemm)
  float* qkv   = ws + 524288;         // 1572864 floats (dead after rope)
  float* Opart = ws;                  // 2097152 floats, reuses h_ln+qkv
  float* qb    = ws + 2097152;        // 524288 each
  float* kb    = qb + 524288;
  float* vb    = kb + 524288;
  float* attn  = vb + 524288;
  float* ml    = (float*)d_out;       // 131072 floats scratch; final gemm
                                      // fully rewrites d_out afterwards

  ln_kernel<<<2048, 256, 0, stream>>>(x, ln_g, ln_b, h_ln);
  gemm_kernel<<<dim3(12, 32), 256, 0, stream>>>(h_ln, w_qkv, nullptr, qkv, 2048, 768, 256);
  rope_split<<<2048, 256, 0, stream>>>(qkv, qb, kb, vb);
  attn_kernel<<<1024, 256, 0, stream>>>(qb, kb, vb, coords, vels, w1, b1, w2, b2, Opart, ml);
  combine_kernel<<<256, 256, 0, stream>>>(Opart, ml, attn);
  gemm_kernel<<<dim3(4, 32), 256, 0, stream>>>(attn, w_o, b_o, out, 2048, 256, 256);
}

// Round 4
// 356.396 us; speedup vs baseline: 1.5104x; 1.1895x over previous
//
#include <hip/hip_runtime.h>
#include <hip/hip_bf16.h>
#include <hip/hip_fp16.h>
#include <math.h>

// ---------------------------------------------------------------------------
// LayerNorm: one block per row (256 elems), block=256
// ---------------------------------------------------------------------------
__global__ __launch_bounds__(256) void ln_kernel(const float* __restrict__ x,
                                                 const float* __restrict__ g,
                                                 const float* __restrict__ bv,
                                                 float* __restrict__ h) {
  int row = blockIdx.x, t = threadIdx.x;
  float v = x[(size_t)row * 256 + t];
  float s = v, q = v * v;
#pragma unroll
  for (int o = 32; o > 0; o >>= 1) {
    s += __shfl_xor(s, o);
    q += __shfl_xor(q, o);
  }
  __shared__ float ss[4], qq[4];
  int w = t >> 6, l = t & 63;
  if (l == 0) { ss[w] = s; qq[w] = q; }
  __syncthreads();
  s = ss[0] + ss[1] + ss[2] + ss[3];
  q = qq[0] + qq[1] + qq[2] + qq[3];
  float mu = s * (1.f / 256.f);
  float var = q * (1.f / 256.f) - mu * mu;
  float inv = rsqrtf(var + 1e-5f);
  h[(size_t)row * 256 + t] = (v - mu) * inv * g[t] + bv[t];
}

// ---------------------------------------------------------------------------
// Tiled fp32 GEMM: C[M,N] = A[M,K] @ B[K,N] (+ bias[n]); BM=BN=64, BK=16
// ---------------------------------------------------------------------------
__global__ __launch_bounds__(256) void gemm_kernel(const float* __restrict__ A,
                                                   const float* __restrict__ Bm,
                                                   const float* __restrict__ bias,
                                                   float* __restrict__ C,
                                                   int M, int N, int K) {
  const int BK = 16;
  __shared__ float As[BK][64];
  __shared__ float Bs[BK][64];
  int tx = threadIdx.x & 15, ty = threadIdx.x >> 4;
  int m0 = blockIdx.y * 64, n0 = blockIdx.x * 64;
  float acc[4][4] = {};
  for (int k0 = 0; k0 < K; k0 += BK) {
    {
      int r = threadIdx.x >> 2;
      int c4 = (threadIdx.x & 3) * 4;
      float4 a = *(const float4*)&A[(size_t)(m0 + r) * K + k0 + c4];
      As[c4 + 0][r] = a.x; As[c4 + 1][r] = a.y;
      As[c4 + 2][r] = a.z; As[c4 + 3][r] = a.w;
    }
    {
      int kk = threadIdx.x >> 4;
      int c4 = (threadIdx.x & 15) * 4;
      *(float4*)&Bs[kk][c4] = *(const float4*)&Bm[(size_t)(k0 + kk) * N + n0 + c4];
    }
    __syncthreads();
#pragma unroll
    for (int kk = 0; kk < BK; kk++) {
      float a[4], bb[4];
#pragma unroll
      for (int r = 0; r < 4; r++) a[r] = As[kk][ty * 4 + r];
#pragma unroll
      for (int c = 0; c < 4; c++) bb[c] = Bs[kk][tx * 4 + c];
#pragma unroll
      for (int r = 0; r < 4; r++)
#pragma unroll
        for (int c = 0; c < 4; c++) acc[r][c] = fmaf(a[r], bb[c], acc[r][c]);
    }
    __syncthreads();
  }
#pragma unroll
  for (int r = 0; r < 4; r++) {
    int row = m0 + ty * 4 + r;
#pragma unroll
    for (int c = 0; c < 4; c++) {
      int col = n0 + tx * 4 + c;
      float val = acc[r][c] + (bias ? bias[col] : 0.f);
      C[(size_t)row * N + col] = val;
    }
  }
}

// ---------------------------------------------------------------------------
// RoPE + split qkv (2048 x 768) -> q,k,v in (B,H,N,D) layout
// ---------------------------------------------------------------------------
__global__ __launch_bounds__(256) void rope_split(const float* __restrict__ qkv,
                                                  float* __restrict__ qo,
                                                  float* __restrict__ ko,
                                                  float* __restrict__ vo) {
  int row = blockIdx.x;           // b*1024 + n
  int b = row >> 10, n = row & 1023;
  int t = threadIdx.x;            // h*32 + d
  int hh = t >> 5, d = t & 31;
  const float* base = qkv + (size_t)row * 768;
  float vv = base[512 + t];
  int f = d & 15;
  float inv_freq = powf(10000.0f, -(float)f / 16.0f);
  float ang = (float)n * inv_freq;
  float sn, cs;
  sincosf(ang, &sn, &cs);
  float q1 = base[hh * 32 + f], q2 = base[hh * 32 + f + 16];
  float k1 = base[256 + hh * 32 + f], k2 = base[256 + hh * 32 + f + 16];
  float qr = (d < 16) ? (q1 * cs - q2 * sn) : (q2 * cs + q1 * sn);
  float kr = (d < 16) ? (k1 * cs - k2 * sn) : (k2 * cs + k1 * sn);
  size_t oidx = ((size_t)(b * 8 + hh) * 1024 + n) * 32 + d;
  qo[oidx] = qr;
  ko[oidx] = kr;
  vo[oidx] = vv;
}

// ---------------------------------------------------------------------------
// Fast exact GELU via Abramowitz-Stegun 7.1.26 erf (max err 1.5e-7)
// ---------------------------------------------------------------------------
__device__ __forceinline__ float gelu_fast(float z) {
  float s = z * 0.70710678118654752f;
  float a = fabsf(s);
  float t = __builtin_amdgcn_rcpf(fmaf(0.3275911f, a, 1.0f));
  float poly = t * fmaf(t, fmaf(t, fmaf(t, fmaf(t, 1.061405429f, -1.453152027f),
                                        1.421413741f),
                                -0.284496736f),
                        0.254829592f);
  float e = __expf(-a * a);
  float erf_a = fmaf(-poly, e, 1.0f);
  float erf_s = copysignf(erf_a, s);
  return 0.5f * z * (1.0f + erf_s);
}

// ---------------------------------------------------------------------------
// Relational bias MLP -> rel[b][h][i][jrel] (fp16), jrel = j - j_base.
// Streaming: one barrier (weight staging), then pure compute. Each thread
// computes one i and TWO adjacent j (weight-read reuse, half2 stores).
// grid = 2 * 128 * (jspan/64) blocks, 256 threads (th=i 0..7, tl=j-pair 0..31).
// ---------------------------------------------------------------------------
__global__ __launch_bounds__(256) void rel_kernel(
    const float* __restrict__ coords, const float* __restrict__ vels,
    const float* __restrict__ w1, const float* __restrict__ b1,
    const float* __restrict__ w2, const float* __restrict__ b2,
    __half* __restrict__ rel, int j_base, int jspan) {
  const int bx = blockIdx.x;
  const int it = bx & 127;
  const int rest = bx >> 7;
  const int nj = jspan >> 6;
  const int jt = rest % nj;
  const int b = rest / nj;
  const int t = threadIdx.x;
  const int th = t >> 5, tl = t & 31;
  const int i = it * 8 + th;
  const int j = j_base + jt * 64 + 2 * tl;

  __shared__ float pack[64][16];  // per-k: w1[0..4][k], b1[k], w2[k][0..7], pad
  {
    int kk = t & 63, f = t >> 6;
    float4 val;
    if (f == 0)
      val = make_float4(w1[kk], w1[64 + kk], w1[128 + kk], w1[192 + kk]);
    else if (f == 1)
      val = make_float4(w1[256 + kk], b1[kk], w2[kk * 8], w2[kk * 8 + 1]);
    else if (f == 2)
      val = make_float4(w2[kk * 8 + 2], w2[kk * 8 + 3], w2[kk * 8 + 4], w2[kk * 8 + 5]);
    else
      val = make_float4(w2[kk * 8 + 6], w2[kk * 8 + 7], 0.f, 0.f);
    *(float4*)&pack[kk][f * 4] = val;
  }
  float2 ci = *(const float2*)&coords[(size_t)(b * 1024 + i) * 2];
  float2 vi = *(const float2*)&vels[(size_t)(b * 1024 + i) * 2];
  float4 cj = *(const float4*)&coords[(size_t)(b * 1024 + j) * 2];  // j and j+1
  float4 vj = *(const float4*)&vels[(size_t)(b * 1024 + j) * 2];
  float dx0a = ci.x - cj.x, dx1a = ci.y - cj.y;
  float dx0b = ci.x - cj.z, dx1b = ci.y - cj.w;
  float dv0a = vi.x - vj.x, dv1a = vi.y - vj.y;
  float dv0b = vi.x - vj.z, dv1b = vi.y - vj.w;
  float dista = sqrtf(dx0a * dx0a + dx1a * dx1a);
  float distb = sqrtf(dx0b * dx0b + dx1b * dx1b);
  float relA[8], relB[8];
#pragma unroll
  for (int h = 0; h < 8; h++) { relA[h] = b2[h]; relB[h] = relA[h]; }
  __syncthreads();

#pragma unroll 4
  for (int kk = 0; kk < 64; kk++) {
    float4 p0 = *(float4*)&pack[kk][0];
    float4 p1 = *(float4*)&pack[kk][4];
    float4 p2 = *(float4*)&pack[kk][8];
    float4 p3 = *(float4*)&pack[kk][12];
    float za = fmaf(dx0a, p0.x, fmaf(dx1a, p0.y, fmaf(dista, p0.z,
               fmaf(dv0a, p0.w, fmaf(dv1a, p1.x, p1.y)))));
    float zb = fmaf(dx0b, p0.x, fmaf(dx1b, p0.y, fmaf(distb, p0.z,
               fmaf(dv0b, p0.w, fmaf(dv1b, p1.x, p1.y)))));
    float ga = gelu_fast(za);
    float gb = gelu_fast(zb);
    relA[0] = fmaf(ga, p1.z, relA[0]);  relB[0] = fmaf(gb, p1.z, relB[0]);
    relA[1] = fmaf(ga, p1.w, relA[1]);  relB[1] = fmaf(gb, p1.w, relB[1]);
    relA[2] = fmaf(ga, p2.x, relA[2]);  relB[2] = fmaf(gb, p2.x, relB[2]);
    relA[3] = fmaf(ga, p2.y, relA[3]);  relB[3] = fmaf(gb, p2.y, relB[3]);
    relA[4] = fmaf(ga, p2.z, relA[4]);  relB[4] = fmaf(gb, p2.z, relB[4]);
    relA[5] = fmaf(ga, p2.w, relA[5]);  relB[5] = fmaf(gb, p2.w, relB[5]);
    relA[6] = fmaf(ga, p3.x, relA[6]);  relB[6] = fmaf(gb, p3.x, relB[6]);
    relA[7] = fmaf(ga, p3.y, relA[7]);  relB[7] = fmaf(gb, p3.y, relB[7]);
  }
  // store as half2, coalesced over tl
  size_t jrel = (size_t)(j - j_base);
#pragma unroll
  for (int h = 0; h < 8; h++) {
    __half2 hv = __halves2half2(__float2half_rn(relA[h]), __float2half_rn(relB[h]));
    *(__half2*)&rel[((size_t)(b * 8 + h) * 1024 + i) * jspan + jrel] = hv;
  }
}

// ---------------------------------------------------------------------------
// Attention: QK^T + rel(fp16, from global) + online softmax + PV.
// njs=4: grid = 2*4*128 (full rel buffer); njs=1: grid = 2*128, js=js0 (chunk).
// Per j-tile of 32: [B: scores+softmax] bar [C: PV] bar.
// ---------------------------------------------------------------------------
__global__ __launch_bounds__(256) void attn_kernel(
    const float* __restrict__ q, const float* __restrict__ k,
    const float* __restrict__ v, const __half* __restrict__ rel,
    int j_base, int jspan, int njs, int js0,
    float* __restrict__ Opart, float* __restrict__ ml) {
  const int ig = blockIdx.x & 127;
  const int rest = blockIdx.x >> 7;
  int js, b;
  if (njs == 4) { js = rest & 3; b = rest >> 2; }
  else          { js = js0;     b = rest; }
  const int i0 = ig * 8;
  const int j0 = js * 256;
  const int t = threadIdx.x;
  const int th = t >> 5;  // h
  const int tl = t & 31;  // j (phase B) / d (phase C)

  __shared__ float Qs[8][256];       // [i][h*32+d]
  __shared__ float pS[8][8][32];     // [h][i][j]
  __shared__ float mS[8][8], lS[8][8], fS[8][8];  // [i][h]

  for (int e = t; e < 2048; e += 256) {
    int i = e >> 8, c = e & 255;
    Qs[i][c] = q[((size_t)(b * 8 + (c >> 5)) * 1024 + i0 + i) * 32 + (c & 31)];
  }
  if (t < 64) { mS[t >> 3][t & 7] = -1e30f; lS[t >> 3][t & 7] = 0.f; }
  float O[8] = {0.f, 0.f, 0.f, 0.f, 0.f, 0.f, 0.f, 0.f};
  __syncthreads();

  const float scale = 0.17677669529663687f;  // 1/sqrt(32)

  for (int jt = j0; jt < j0 + 256; jt += 32) {
    // ---- phase B: scores + rel + online softmax, thread (h=th, j=tl) ----
    {
      const __half* relb = rel + ((size_t)(b * 8 + th) * 1024 + i0) * jspan +
                           (jt + tl - j_base);
      float rv[8];
#pragma unroll
      for (int i = 0; i < 8; i++) rv[i] = __half2float(relb[(size_t)i * jspan]);
      const float* krow = k + ((size_t)(b * 8 + th) * 1024 + jt + tl) * 32;
      float acc[8] = {0.f, 0.f, 0.f, 0.f, 0.f, 0.f, 0.f, 0.f};
#pragma unroll
      for (int e = 0; e < 8; e++) {
        float4 kr = *(const float4*)(krow + e * 4);
#pragma unroll
        for (int i = 0; i < 8; i++) {
          float4 qv = *(const float4*)&Qs[i][th * 32 + e * 4];
          acc[i] = fmaf(qv.x, kr.x,
                   fmaf(qv.y, kr.y,
                   fmaf(qv.z, kr.z, fmaf(qv.w, kr.w, acc[i]))));
        }
      }
#pragma unroll
      for (int i = 0; i < 8; i++) {
        float s = fmaf(acc[i], scale, rv[i]);
        float tm = s;
#pragma unroll
        for (int o = 16; o > 0; o >>= 1) tm = fmaxf(tm, __shfl_xor(tm, o));
        float mo = mS[i][th];
        float nm = fmaxf(mo, tm);
        float fac = __expf(mo - nm);
        float p = __expf(s - nm);
        float ts = p;
#pragma unroll
        for (int o = 16; o > 0; o >>= 1) ts += __shfl_xor(ts, o);
        pS[th][i][tl] = p;
        if (tl == 0) {
          mS[i][th] = nm;
          fS[i][th] = fac;
          lS[i][th] = lS[i][th] * fac + ts;
        }
      }
    }
    __syncthreads();  // pS, fS ready
    // ---- phase C: PV accumulate, thread (h=th, d=tl) ----
    {
      const float* vcol = v + ((size_t)(b * 8 + th) * 1024 + jt) * 32 + tl;
      float acc[8] = {0.f, 0.f, 0.f, 0.f, 0.f, 0.f, 0.f, 0.f};
#pragma unroll 8
      for (int j = 0; j < 32; j++) {
        float vv = vcol[(size_t)j * 32];
#pragma unroll
        for (int i = 0; i < 8; i++) acc[i] = fmaf(pS[th][i][j], vv, acc[i]);
      }
#pragma unroll
      for (int i = 0; i < 8; i++) O[i] = O[i] * fS[i][th] + acc[i];
    }
    __syncthreads();  // pS free for next tile
  }
  size_t obase = ((size_t)((b * 4 + js) * 1024) + i0) * 256;
#pragma unroll
  for (int i = 0; i < 8; i++) Opart[obase + (size_t)i * 256 + t] = O[i];
  if (t < 64) {
    int i = t >> 3, hh = t & 7;
    ((float2*)ml)[(((size_t)(b * 4 + js) * 1024) + i0 + i) * 8 + hh] =
        make_float2(mS[i][hh], lS[i][hh]);
  }
}

// ---------------------------------------------------------------------------
// Combine j-split partials: grid = 256 blocks (b, i-group of 8), 256 threads.
// ---------------------------------------------------------------------------
__global__ __launch_bounds__(256) void combine_kernel(
    const float* __restrict__ Opart, const float* __restrict__ ml,
    float* __restrict__ attn) {
  int b = blockIdx.x >> 7, ig = blockIdx.x & 127;
  int i0 = ig * 8;
  int t = threadIdx.x, hh = t >> 5;
#pragma unroll
  for (int i = 0; i < 8; i++) {
    float2 mls[4];
    float M = -1e30f;
#pragma unroll
    for (int js = 0; js < 4; js++) {
      mls[js] = ((const float2*)ml)[(((size_t)(b * 4 + js) * 1024) + i0 + i) * 8 + hh];
      M = fmaxf(M, mls[js].x);
    }
    float L = 0.f, Ov = 0.f;
#pragma unroll
    for (int js = 0; js < 4; js++) {
      float w = __expf(mls[js].x - M);
      L += mls[js].y * w;
      Ov += Opart[(((size_t)(b * 4 + js) * 1024) + i0 + i) * 256 + t] * w;
    }
    attn[((size_t)b * 1024 + i0 + i) * 256 + t] = Ov / L;
  }
}

// ---------------------------------------------------------------------------
extern "C" void kernel_launch(void* const* d_in, const int* in_sizes, int n_in,
                              void* d_out, int out_size, void* d_ws, size_t ws_size,
                              hipStream_t stream) {
  const float* x      = (const float*)d_in[0];
  const float* coords = (const float*)d_in[1];
  const float* vels   = (const float*)d_in[2];
  const float* ln_g   = (const float*)d_in[3];
  const float* ln_b   = (const float*)d_in[4];
  const float* w_qkv  = (const float*)d_in[5];
  const float* w_o    = (const float*)d_in[6];
  const float* b_o    = (const float*)d_in[7];
  const float* w1     = (const float*)d_in[8];
  const float* b1     = (const float*)d_in[9];
  const float* w2     = (const float*)d_in[10];
  const float* b2     = (const float*)d_in[11];
  float* out = (float*)d_out;

  float* ws    = (float*)d_ws;
  float* h_ln  = ws;                  // 524288 floats (dead after qkv gemm)
  float* qkv   = ws + 524288;         // 1572864 floats (dead after rope)
  float* Opart = ws;                  // 2097152 floats, reuses h_ln+qkv
  float* qb    = ws + 2097152;
  float* kb    = qb + 524288;
  float* vb    = kb + 524288;
  float* attn  = vb + 524288;         // ends at float 4194304 = byte 16777216
  __half* relh = (__half*)((char*)d_ws + 16777216);
  float* ml    = (float*)d_out;       // 131072 floats scratch; final gemm
                                      // fully rewrites d_out afterwards

  ln_kernel<<<2048, 256, 0, stream>>>(x, ln_g, ln_b, h_ln);
  gemm_kernel<<<dim3(12, 32), 256, 0, stream>>>(h_ln, w_qkv, nullptr, qkv, 2048, 768, 256);
  rope_split<<<2048, 256, 0, stream>>>(qkv, qb, kb, vb);

  const size_t full_bytes = 16777216ull + 2ull * 8 * 1024 * 1024 * 2;  // 50.3 MB
  if (ws_size >= full_bytes) {
    // full rel buffer: [b][h][i][1024] fp16
    rel_kernel<<<2 * 128 * 16, 256, 0, stream>>>(coords, vels, w1, b1, w2, b2,
                                                 relh, 0, 1024);
    attn_kernel<<<1024, 256, 0, stream>>>(qb, kb, vb, relh, 0, 1024, 4, 0,
                                          Opart, ml);
  } else {
    // chunked: rel buffer holds one j-chunk of 256 -> 8.4 MB
    for (int c = 0; c < 4; c++) {
      rel_kernel<<<2 * 128 * 4, 256, 0, stream>>>(coords, vels, w1, b1, w2, b2,
                                                  relh, c * 256, 256);
      attn_kernel<<<256, 256, 0, stream>>>(qb, kb, vb, relh, c * 256, 256, 1, c,
                                           Opart, ml);
    }
  }
  combine_kernel<<<256, 256, 0, stream>>>(Opart, ml, attn);
  gemm_kernel<<<dim3(4, 32), 256, 0, stream>>>(attn, w_o, b_o, out, 2048, 256, 256);
}